// Round 3
// baseline (304.784 us; speedup 1.0000x reference)
//
#include <hip/hip_runtime.h>
#include <stdint.h>

#define B  8
#define TE 2048
#define TD 256
#define H  128

// arg is pre-scaled: x2c = 2*log2(e)*x ; returns tanh(x) = 1 - 2/(exp(2x)+1)
__device__ __forceinline__ float tanh_pre(float x2c) {
  float e = __builtin_amdgcn_exp2f(x2c);
  float r = __builtin_amdgcn_rcpf(e + 1.0f);
  return 1.0f - 2.0f * r;   // large +x -> e=inf -> 1 ; large -x -> e=0 -> -1
}

// ---------- kernel 1: wenc = enc@W_a * 2log2e ; udec = dec@U_a * 2log2e ----------
__global__ __launch_bounds__(256) void proj_kernel(
    const float* __restrict__ enc, const float* __restrict__ dec,
    const float* __restrict__ Wa,  const float* __restrict__ Ua,
    float* __restrict__ wenc, float* __restrict__ udec) {
  __shared__ float Mu[64 * 128];     // 32 KB: k-chunk of weight [k][h]
  __shared__ float rowsU[16 * 128];  // 8 KB: 16 input rows
  const float C2 = 2.8853900817779268f;  // 2*log2(e)
  int tid = threadIdx.x;
  int r0 = blockIdx.x * 16;              // wenc/udec boundary (16384) is block-aligned
  const float* Mg; const float* in; float* out; int rbase;
  if (r0 < B * TE) { Mg = Wa; in = enc; out = wenc; rbase = r0; }
  else             { Mg = Ua; in = dec; out = udec; rbase = r0 - B * TE; }
  ((float4*)rowsU)[tid]       = ((const float4*)(in + (size_t)rbase * H))[tid];
  ((float4*)rowsU)[tid + 256] = ((const float4*)(in + (size_t)rbase * H))[tid + 256];
  int h = tid & 127, rl = tid >> 7;
  float acc[8];
  #pragma unroll
  for (int p = 0; p < 8; ++p) acc[p] = 0.f;
  for (int kc = 0; kc < 128; kc += 64) {
    __syncthreads();                       // also covers rowsU visibility on kc==0
    #pragma unroll
    for (int i = 0; i < 8; ++i) {          // 64x128 floats = 2048 float4
      int f = tid + i * 256;
      ((float4*)Mu)[f] = ((const float4*)(Mg + (size_t)kc * H))[f];
    }
    __syncthreads();
    #pragma unroll
    for (int p = 0; p < 8; ++p) {
      int r = p * 2 + rl;
      float a = 0.f;
      #pragma unroll 8
      for (int k = 0; k < 64; ++k)
        a += rowsU[r * 128 + kc + k] * Mu[k * 128 + h];
      acc[p] += a;
    }
  }
  #pragma unroll
  for (int p = 0; p < 8; ++p)
    out[(size_t)(rbase + p * 2 + rl) * H + h] = acc[p] * C2;
}

// ---------- kernel 2: scores[b,j,t] = sum_k v_k * tanh(w+u)  (537M-tanh hot loop) ----------
__global__ __launch_bounds__(512, 4) void scores_kernel(
    const float* __restrict__ wenc, const float* __restrict__ udec,
    const float* __restrict__ Va, float* __restrict__ scores) {
  __shared__ float W[64 * 132];   // 33.8 KB, padded stride 132 (conflict-free b128)
  __shared__ float U[8 * 132];    // 4.2 KB
  __shared__ float Vv[128];
  int tid = threadIdx.x;
  int tc = blockIdx.x, jt = blockIdx.y, b = blockIdx.z;
  int j0 = jt * 8;
  #pragma unroll
  for (int i = 0; i < 2; ++i) {   // 8 x 128 udec rows
    int idx = tid + i * 512;
    int j = idx >> 7, k = idx & 127;
    U[j * 132 + k] = udec[(size_t)(b * TD + j0 + j) * H + k];
  }
  if (tid < 128) Vv[tid] = Va[tid];
  int lane = tid & 63, jj = tid >> 6;          // wave-uniform j -> U/V reads broadcast
  const float* urow = &U[jj * 132];
  const float* wrow = &W[lane * 132];
  int tbase = tc * 512;
  for (int tt = 0; tt < 512; tt += 64) {
    __syncthreads();
    const float* wg = wenc + (size_t)(b * TE + tbase + tt) * H;
    #pragma unroll
    for (int i = 0; i < 4; ++i) {              // 2048 float4, coalesced
      int f4 = tid + i * 512;
      int tr = f4 >> 5, kc = (f4 & 31) * 4;
      *(float4*)&W[tr * 132 + kc] = ((const float4*)wg)[f4];
    }
    __syncthreads();
    float s0 = 0.f;
    #pragma unroll 4
    for (int k = 0; k < 128; k += 4) {
      float4 u4 = *(const float4*)(urow + k);
      float4 v4 = *(const float4*)(Vv + k);
      float4 a4 = *(const float4*)(wrow + k);
      s0 += v4.x * tanh_pre(a4.x + u4.x);
      s0 += v4.y * tanh_pre(a4.y + u4.y);
      s0 += v4.z * tanh_pre(a4.z + u4.z);
      s0 += v4.w * tanh_pre(a4.w + u4.w);
    }
    scores[(size_t)(b * TD + j0 + jj) * TE + tbase + tt + lane] = s0;
  }
}

// ---------- kernel 3: softmax over t; e (fp32) straight into d_out ----------
__global__ __launch_bounds__(256) void softmax_kernel(
    const float* __restrict__ scores, float* __restrict__ eout) {
  __shared__ float red[4];
  int r = blockIdx.x, tid = threadIdx.x;
  const float* row = scores + (size_t)r * TE;
  float4 a = ((const float4*)row)[tid];
  float4 c = ((const float4*)row)[tid + 256];
  float m = fmaxf(fmaxf(fmaxf(a.x, a.y), fmaxf(a.z, a.w)),
                  fmaxf(fmaxf(c.x, c.y), fmaxf(c.z, c.w)));
  #pragma unroll
  for (int off = 32; off > 0; off >>= 1) m = fmaxf(m, __shfl_xor(m, off));
  int w = tid >> 6;
  if ((tid & 63) == 0) red[w] = m;
  __syncthreads();
  m = fmaxf(fmaxf(red[0], red[1]), fmaxf(red[2], red[3]));
  const float L2E = 1.4426950408889634f;
  a.x = __builtin_amdgcn_exp2f((a.x - m) * L2E);
  a.y = __builtin_amdgcn_exp2f((a.y - m) * L2E);
  a.z = __builtin_amdgcn_exp2f((a.z - m) * L2E);
  a.w = __builtin_amdgcn_exp2f((a.w - m) * L2E);
  c.x = __builtin_amdgcn_exp2f((c.x - m) * L2E);
  c.y = __builtin_amdgcn_exp2f((c.y - m) * L2E);
  c.z = __builtin_amdgcn_exp2f((c.z - m) * L2E);
  c.w = __builtin_amdgcn_exp2f((c.w - m) * L2E);
  float s = a.x + a.y + a.z + a.w + c.x + c.y + c.z + c.w;
  #pragma unroll
  for (int off = 32; off > 0; off >>= 1) s += __shfl_xor(s, off);
  __syncthreads();                 // red[] reuse
  if ((tid & 63) == 0) red[w] = s;
  __syncthreads();
  s = red[0] + red[1] + red[2] + red[3];
  float inv = 1.0f / s;            // precise div, once per thread
  a.x *= inv; a.y *= inv; a.z *= inv; a.w *= inv;
  c.x *= inv; c.y *= inv; c.z *= inv; c.w *= inv;
  float* orow = eout + (size_t)r * TE;
  ((float4*)orow)[tid] = a;
  ((float4*)orow)[tid + 256] = c;
}

// ---------- kernel 4: c[b,j,:] = sum_t e[b,j,t] * enc[b,t,:]  (fp32 out) ----------
__global__ __launch_bounds__(512) void context_kernel(
    const float* __restrict__ enc, const float* __restrict__ e,
    float* __restrict__ cout) {
  __shared__ float Et[64 * 132];   // 33.8 KB enc tile [t][h], padded
  __shared__ float P[8 * 64];      // e tile [j][t]
  int tid = threadIdx.x;
  int jt = blockIdx.x, b = blockIdx.y;
  int j0 = jt * 8;
  int h = tid & 127, slot = tid >> 7;           // thread owns (slot,h) and (slot+4,h)
  float acc0 = 0.f, acc1 = 0.f;
  for (int tt = 0; tt < TE; tt += 64) {
    __syncthreads();
    const float4* eg = (const float4*)(enc + ((size_t)b * TE + tt) * H);
    #pragma unroll
    for (int i = 0; i < 4; ++i) {               // 64x128 floats = 2048 float4
      int f = tid + i * 512;
      int tr = f >> 5, kc = (f & 31) * 4;
      *(float4*)&Et[tr * 132 + kc] = eg[f];
    }
    {
      int j = tid >> 6, tl = tid & 63;
      P[j * 64 + tl] = e[(size_t)(b * TD + j0 + j) * TE + tt + tl];
    }
    __syncthreads();
    #pragma unroll 16
    for (int tl = 0; tl < 64; ++tl) {
      float ec = Et[tl * 132 + h];              // shared between both j's
      acc0 += P[slot * 64 + tl] * ec;           // P reads are wave-broadcast
      acc1 += P[(slot + 4) * 64 + tl] * ec;
    }
  }
  cout[(size_t)(b * TD + j0 + slot) * H + h]     = acc0;
  cout[(size_t)(b * TD + j0 + slot + 4) * H + h] = acc1;
}

extern "C" void kernel_launch(void* const* d_in, const int* in_sizes, int n_in,
                              void* d_out, int out_size, void* d_ws, size_t ws_size,
                              hipStream_t stream) {
  (void)in_sizes; (void)n_in; (void)out_size; (void)ws_size;
  const float* enc = (const float*)d_in[0];
  const float* dec = (const float*)d_in[1];
  const float* Wa  = (const float*)d_in[2];
  const float* Ua  = (const float*)d_in[3];
  const float* Va  = (const float*)d_in[4];

  float* ws     = (float*)d_ws;
  float* wenc   = ws;                                    //  2,097,152 f32 (8 MB)
  float* udec   = wenc + (size_t)B * TE * H;             //    262,144 f32 (1 MB)
  float* scores = udec + (size_t)B * TD * H;             //  4,194,304 f32 (16 MB)
  float* outc = (float*)d_out;                           // c [B,TD,H] fp32
  float* oute = outc + (size_t)B * TD * H;               // e [B,TD,TE] fp32

  proj_kernel<<<dim3((B * TE + B * TD) / 16), 256, 0, stream>>>(enc, dec, Wa, Ua, wenc, udec);
  scores_kernel<<<dim3(4, 32, 8), 512, 0, stream>>>(wenc, udec, Va, scores);
  softmax_kernel<<<dim3(B * TD), 256, 0, stream>>>(scores, oute);
  context_kernel<<<dim3(32, 8), 512, 0, stream>>>(enc, oute, outc);
}

// Round 4
// 223.773 us; speedup vs baseline: 1.3620x; 1.3620x over previous
//
#include <hip/hip_runtime.h>
#include <stdint.h>

#define B  8
#define TE 2048
#define TD 256
#define H  128

// ---------- kernel 0: zero the c region of d_out (re-poisoned 0xAA each call) ----------
__global__ __launch_bounds__(256) void zero_c_kernel(float4* __restrict__ c4) {
  c4[blockIdx.x * 256 + threadIdx.x] = float4{0.f, 0.f, 0.f, 0.f};
}

// ---------- kernel 1: E = exp(2*enc@W_a) ; F = exp(2*dec@U_a) ----------
__global__ __launch_bounds__(256) void proj_kernel(
    const float* __restrict__ enc, const float* __restrict__ dec,
    const float* __restrict__ Wa,  const float* __restrict__ Ua,
    float* __restrict__ Eo, float* __restrict__ Fo) {
  __shared__ float Mu[64 * 128];     // 32 KB: k-chunk of weight [k][h]
  __shared__ float rowsU[16 * 128];  // 8 KB: 16 input rows
  const float C2 = 2.8853900817779268f;  // 2*log2(e):  exp(2x) = exp2(C2*x)
  int tid = threadIdx.x;
  int r0 = blockIdx.x * 16;              // E/F boundary (16384) is block-aligned
  const float* Mg; const float* in; float* out; int rbase;
  if (r0 < B * TE) { Mg = Wa; in = enc; out = Eo; rbase = r0; }
  else             { Mg = Ua; in = dec; out = Fo; rbase = r0 - B * TE; }
  ((float4*)rowsU)[tid]       = ((const float4*)(in + (size_t)rbase * H))[tid];
  ((float4*)rowsU)[tid + 256] = ((const float4*)(in + (size_t)rbase * H))[tid + 256];
  int h = tid & 127, rl = tid >> 7;
  float acc[8];
  #pragma unroll
  for (int p = 0; p < 8; ++p) acc[p] = 0.f;
  for (int kc = 0; kc < 128; kc += 64) {
    __syncthreads();                       // also covers rowsU visibility on kc==0
    #pragma unroll
    for (int i = 0; i < 8; ++i) {          // 64x128 floats = 2048 float4
      int f = tid + i * 256;
      ((float4*)Mu)[f] = ((const float4*)(Mg + (size_t)kc * H))[f];
    }
    __syncthreads();
    #pragma unroll
    for (int p = 0; p < 8; ++p) {
      int r = p * 2 + rl;
      float a = 0.f;
      #pragma unroll 8
      for (int k = 0; k < 64; ++k)
        a += rowsU[r * 128 + kc + k] * Mu[k * 128 + h];
      acc[p] += a;
    }
  }
  #pragma unroll
  for (int p = 0; p < 8; ++p)
    out[(size_t)(rbase + p * 2 + rl) * H + h] = __builtin_amdgcn_exp2f(acc[p] * C2);
}

// ---------- kernel 2: scores[b,j,t] = V1 - 2*sum_k v_k / (E[t,k]*F[j,k] + 1) ----------
// (identity: v*tanh(w+u) = v - 2v/(e^{2w}e^{2u}+1); the 537M exps are amortized into E,F)
__global__ __launch_bounds__(512) void scores_kernel(
    const float* __restrict__ Eg, const float* __restrict__ Fg,
    const float* __restrict__ Va, float* __restrict__ scores) {
  __shared__ float Es[64 * 132];   // 33.8 KB, padded stride 132
  __shared__ float Fs[16 * 132];   // 8.4 KB: 16 decoder rows
  __shared__ float Vv[128];
  int tid = threadIdx.x;
  int tc = blockIdx.x, jt = blockIdx.y, b = blockIdx.z;
  int j0 = jt * 16;
  #pragma unroll
  for (int i = 0; i < 4; ++i) {    // 16 x 128 F rows
    int idx = tid + i * 512;
    int j = idx >> 7, k = idx & 127;
    Fs[j * 132 + k] = Fg[(size_t)(b * TD + j0 + j) * H + k];
  }
  if (tid < 128) Vv[tid] = Va[tid];
  __syncthreads();
  float V1 = 0.f;                  // sum_k v_k  (broadcast reads, once per block)
  #pragma unroll
  for (int k = 0; k < 128; k += 4) {
    float4 v4 = *(const float4*)(Vv + k);
    V1 += v4.x + v4.y + v4.z + v4.w;
  }
  int lane = tid & 63, w = tid >> 6;           // wave handles j = {w, w+8}
  const float* erow = &Es[lane * 132];
  const float* fa = &Fs[w * 132];
  const float* fb = &Fs[(w + 8) * 132];
  int tbase = tc * 256;
  for (int tt = 0; tt < 256; tt += 64) {
    __syncthreads();
    const float* eg = Eg + (size_t)(b * TE + tbase + tt) * H;
    #pragma unroll
    for (int i = 0; i < 4; ++i) {              // 2048 float4, coalesced
      int f4 = tid + i * 512;
      int tr = f4 >> 5, kc = (f4 & 31) * 4;
      *(float4*)&Es[tr * 132 + kc] = ((const float4*)eg)[f4];
    }
    __syncthreads();
    float s0 = 0.f, s1 = 0.f;
    #pragma unroll 4
    for (int k = 0; k < 128; k += 4) {
      float4 e4 = *(const float4*)(erow + k);
      float4 a4 = *(const float4*)(fa + k);
      float4 b4 = *(const float4*)(fb + k);
      float4 v4 = *(const float4*)(Vv + k);
      s0 += v4.x * __builtin_amdgcn_rcpf(fmaf(e4.x, a4.x, 1.0f));
      s0 += v4.y * __builtin_amdgcn_rcpf(fmaf(e4.y, a4.y, 1.0f));
      s0 += v4.z * __builtin_amdgcn_rcpf(fmaf(e4.z, a4.z, 1.0f));
      s0 += v4.w * __builtin_amdgcn_rcpf(fmaf(e4.w, a4.w, 1.0f));
      s1 += v4.x * __builtin_amdgcn_rcpf(fmaf(e4.x, b4.x, 1.0f));
      s1 += v4.y * __builtin_amdgcn_rcpf(fmaf(e4.y, b4.y, 1.0f));
      s1 += v4.z * __builtin_amdgcn_rcpf(fmaf(e4.z, b4.z, 1.0f));
      s1 += v4.w * __builtin_amdgcn_rcpf(fmaf(e4.w, b4.w, 1.0f));
    }
    int t = tbase + tt + lane;
    scores[(size_t)(b * TD + j0 + w) * TE + t]     = V1 - 2.0f * s0;
    scores[(size_t)(b * TD + j0 + w + 8) * TE + t] = V1 - 2.0f * s1;
  }
}

// ---------- kernel 3: softmax over t; e (fp32) straight into d_out ----------
__global__ __launch_bounds__(256) void softmax_kernel(
    const float* __restrict__ scores, float* __restrict__ eout) {
  __shared__ float red[4];
  int r = blockIdx.x, tid = threadIdx.x;
  const float* row = scores + (size_t)r * TE;
  float4 a = ((const float4*)row)[tid];
  float4 c = ((const float4*)row)[tid + 256];
  float m = fmaxf(fmaxf(fmaxf(a.x, a.y), fmaxf(a.z, a.w)),
                  fmaxf(fmaxf(c.x, c.y), fmaxf(c.z, c.w)));
  #pragma unroll
  for (int off = 32; off > 0; off >>= 1) m = fmaxf(m, __shfl_xor(m, off));
  int w = tid >> 6;
  if ((tid & 63) == 0) red[w] = m;
  __syncthreads();
  m = fmaxf(fmaxf(red[0], red[1]), fmaxf(red[2], red[3]));
  const float L2E = 1.4426950408889634f;
  a.x = __builtin_amdgcn_exp2f((a.x - m) * L2E);
  a.y = __builtin_amdgcn_exp2f((a.y - m) * L2E);
  a.z = __builtin_amdgcn_exp2f((a.z - m) * L2E);
  a.w = __builtin_amdgcn_exp2f((a.w - m) * L2E);
  c.x = __builtin_amdgcn_exp2f((c.x - m) * L2E);
  c.y = __builtin_amdgcn_exp2f((c.y - m) * L2E);
  c.z = __builtin_amdgcn_exp2f((c.z - m) * L2E);
  c.w = __builtin_amdgcn_exp2f((c.w - m) * L2E);
  float s = a.x + a.y + a.z + a.w + c.x + c.y + c.z + c.w;
  #pragma unroll
  for (int off = 32; off > 0; off >>= 1) s += __shfl_xor(s, off);
  __syncthreads();                 // red[] reuse
  if ((tid & 63) == 0) red[w] = s;
  __syncthreads();
  s = red[0] + red[1] + red[2] + red[3];
  float inv = 1.0f / s;            // precise div, once per thread
  a.x *= inv; a.y *= inv; a.z *= inv; a.w *= inv;
  c.x *= inv; c.y *= inv; c.z *= inv; c.w *= inv;
  float* orow = eout + (size_t)r * TE;
  ((float4*)orow)[tid] = a;
  ((float4*)orow)[tid + 256] = c;
}

// ---------- kernel 4: c[b,j,:] += sum_{t in chunk} e[b,j,t]*enc[b,t,:] (atomic combine) ----------
__global__ __launch_bounds__(512) void context_kernel(
    const float* __restrict__ enc, const float* __restrict__ e,
    float* __restrict__ cout) {
  __shared__ float Et[64 * 132];   // 33.8 KB enc tile [t][h], padded
  __shared__ float P[32 * 64];     // 8 KB e tile [j][t] (writes conflict-free, reads broadcast)
  int tid = threadIdx.x;
  int jt = blockIdx.x, tch = blockIdx.y, b = blockIdx.z;
  int j0 = jt * 32, t0 = tch * 256;
  int h = tid & 127, jg = tid >> 7;             // jg wave-uniform (0..3); 8 j's per thread
  float acc[8];
  #pragma unroll
  for (int p = 0; p < 8; ++p) acc[p] = 0.f;
  for (int tt = 0; tt < 256; tt += 64) {
    __syncthreads();
    const float4* eg = (const float4*)(enc + ((size_t)b * TE + t0 + tt) * H);
    #pragma unroll
    for (int i = 0; i < 4; ++i) {               // 64x128 floats = 2048 float4
      int f = tid + i * 512;
      int tr = f >> 5, kc = (f & 31) * 4;
      *(float4*)&Et[tr * 132 + kc] = eg[f];
    }
    #pragma unroll
    for (int pass = 0; pass < 4; ++pass) {      // 32 j x 64 t e-tile
      int j = pass * 8 + (tid >> 6), tl = tid & 63;
      P[j * 64 + tl] = e[(size_t)(b * TD + j0 + j) * TE + t0 + tt + tl];
    }
    __syncthreads();
    #pragma unroll 4
    for (int tl4 = 0; tl4 < 64; tl4 += 4) {
      float ec0 = Et[(tl4 + 0) * 132 + h];
      float ec1 = Et[(tl4 + 1) * 132 + h];
      float ec2 = Et[(tl4 + 2) * 132 + h];
      float ec3 = Et[(tl4 + 3) * 132 + h];
      #pragma unroll
      for (int p = 0; p < 8; ++p) {
        float4 p4 = *(const float4*)&P[(jg * 8 + p) * 64 + tl4];  // broadcast b128
        acc[p] += p4.x * ec0 + p4.y * ec1 + p4.z * ec2 + p4.w * ec3;
      }
    }
  }
  #pragma unroll
  for (int p = 0; p < 8; ++p)
    atomicAdd(&cout[(size_t)(b * TD + j0 + jg * 8 + p) * H + h], acc[p]);
}

extern "C" void kernel_launch(void* const* d_in, const int* in_sizes, int n_in,
                              void* d_out, int out_size, void* d_ws, size_t ws_size,
                              hipStream_t stream) {
  (void)in_sizes; (void)n_in; (void)out_size; (void)ws_size;
  const float* enc = (const float*)d_in[0];
  const float* dec = (const float*)d_in[1];
  const float* Wa  = (const float*)d_in[2];
  const float* Ua  = (const float*)d_in[3];
  const float* Va  = (const float*)d_in[4];

  float* ws     = (float*)d_ws;
  float* Ebuf   = ws;                                    //  2,097,152 f32 (8 MB)  e^{2*enc@W}
  float* Fbuf   = Ebuf + (size_t)B * TE * H;             //    262,144 f32 (1 MB)  e^{2*dec@U}
  float* scores = Fbuf + (size_t)B * TD * H;             //  4,194,304 f32 (16 MB)
  float* outc = (float*)d_out;                           // c [B,TD,H] fp32
  float* oute = outc + (size_t)B * TD * H;               // e [B,TD,TE] fp32

  zero_c_kernel<<<dim3(256), 256, 0, stream>>>((float4*)outc);
  proj_kernel<<<dim3((B * TE + B * TD) / 16), 256, 0, stream>>>(enc, dec, Wa, Ua, Ebuf, Fbuf);
  scores_kernel<<<dim3(8, 16, 8), 512, 0, stream>>>(Ebuf, Fbuf, Va, scores);
  softmax_kernel<<<dim3(B * TD), 256, 0, stream>>>(scores, oute);
  context_kernel<<<dim3(8, 8, 8), 512, 0, stream>>>(enc, oute, outc);
}

// Round 5
// 219.599 us; speedup vs baseline: 1.3879x; 1.0190x over previous
//
#include <hip/hip_runtime.h>
#include <stdint.h>

#define B  8
#define TE 2048
#define TD 256
#define H  128

// ---------- kernel 1: E = exp(2*enc@W_a) ; F = exp(2*dec@U_a) ----------
__global__ __launch_bounds__(256) void proj_kernel(
    const float* __restrict__ enc, const float* __restrict__ dec,
    const float* __restrict__ Wa,  const float* __restrict__ Ua,
    float* __restrict__ Eo, float* __restrict__ Fo) {
  __shared__ float Mu[64 * 128];     // 32 KB: k-chunk of weight [k][h]
  __shared__ float rowsU[16 * 128];  // 8 KB: 16 input rows
  const float C2 = 2.8853900817779268f;  // 2*log2(e):  exp(2x) = exp2(C2*x)
  int tid = threadIdx.x;
  int r0 = blockIdx.x * 16;              // E/F boundary (16384) is block-aligned
  const float* Mg; const float* in; float* out; int rbase;
  if (r0 < B * TE) { Mg = Wa; in = enc; out = Eo; rbase = r0; }
  else             { Mg = Ua; in = dec; out = Fo; rbase = r0 - B * TE; }
  ((float4*)rowsU)[tid]       = ((const float4*)(in + (size_t)rbase * H))[tid];
  ((float4*)rowsU)[tid + 256] = ((const float4*)(in + (size_t)rbase * H))[tid + 256];
  int h = tid & 127, rl = tid >> 7;
  float acc[8];
  #pragma unroll
  for (int p = 0; p < 8; ++p) acc[p] = 0.f;
  for (int kc = 0; kc < 128; kc += 64) {
    __syncthreads();                       // also covers rowsU visibility on kc==0
    #pragma unroll
    for (int i = 0; i < 8; ++i) {          // 64x128 floats = 2048 float4
      int f = tid + i * 256;
      ((float4*)Mu)[f] = ((const float4*)(Mg + (size_t)kc * H))[f];
    }
    __syncthreads();
    #pragma unroll
    for (int p = 0; p < 8; ++p) {
      int r = p * 2 + rl;
      float a = 0.f;
      #pragma unroll 8
      for (int k = 0; k < 64; ++k)
        a += rowsU[r * 128 + kc + k] * Mu[k * 128 + h];
      acc[p] += a;
    }
  }
  #pragma unroll
  for (int p = 0; p < 8; ++p)
    out[(size_t)(rbase + p * 2 + rl) * H + h] = __builtin_amdgcn_exp2f(acc[p] * C2);
}

// ---------- kernel 2: scores[b,j,t] = V1 - 2*sum_k v_k / (E[t,k]*F[j,k] + 1) ----------
// grid 512 blocks = 2/CU resident (capacity 3 at 42.5 KB LDS) -> single round, no tail
__global__ __launch_bounds__(512) void scores_kernel(
    const float* __restrict__ Eg, const float* __restrict__ Fg,
    const float* __restrict__ Va, float* __restrict__ scores) {
  __shared__ float Es[64 * 132];   // 33.8 KB, padded stride 132 (per-lane b128 reads)
  __shared__ float Fs[16 * 128];   // 8 KB (broadcast reads, no padding needed)
  __shared__ float Vv[128];
  int tid = threadIdx.x;
  int tc = blockIdx.x, jt = blockIdx.y, b = blockIdx.z;
  int j0 = jt * 16;
  #pragma unroll
  for (int i = 0; i < 4; ++i) {    // 16 x 128 F rows
    int idx = tid + i * 512;
    ((float*)Fs)[idx] = Fg[(size_t)(b * TD + j0) * H + idx];
  }
  if (tid < 128) Vv[tid] = Va[tid];
  __syncthreads();
  float V1 = 0.f;                  // sum_k v_k  (broadcast reads, once per block)
  #pragma unroll
  for (int k = 0; k < 128; k += 4) {
    float4 v4 = *(const float4*)(Vv + k);
    V1 += v4.x + v4.y + v4.z + v4.w;
  }
  int lane = tid & 63, w = tid >> 6;           // wave handles j = {w, w+8}
  const float* erow = &Es[lane * 132];
  const float* fa = &Fs[w * 128];
  const float* fb = &Fs[(w + 8) * 128];
  int tbase = tc * 512;
  for (int tt = 0; tt < 512; tt += 64) {       // 8 iters
    __syncthreads();
    const float* eg = Eg + (size_t)(b * TE + tbase + tt) * H;
    #pragma unroll
    for (int i = 0; i < 4; ++i) {              // 2048 float4, coalesced
      int f4 = tid + i * 512;
      int tr = f4 >> 5, kc = (f4 & 31) * 4;
      *(float4*)&Es[tr * 132 + kc] = ((const float4*)eg)[f4];
    }
    __syncthreads();
    float s0 = 0.f, s1 = 0.f;
    #pragma unroll 4
    for (int k = 0; k < 128; k += 4) {
      float4 e4 = *(const float4*)(erow + k);
      float4 a4 = *(const float4*)(fa + k);
      float4 b4 = *(const float4*)(fb + k);
      float4 v4 = *(const float4*)(Vv + k);
      s0 += v4.x * __builtin_amdgcn_rcpf(fmaf(e4.x, a4.x, 1.0f));
      s0 += v4.y * __builtin_amdgcn_rcpf(fmaf(e4.y, a4.y, 1.0f));
      s0 += v4.z * __builtin_amdgcn_rcpf(fmaf(e4.z, a4.z, 1.0f));
      s0 += v4.w * __builtin_amdgcn_rcpf(fmaf(e4.w, a4.w, 1.0f));
      s1 += v4.x * __builtin_amdgcn_rcpf(fmaf(e4.x, b4.x, 1.0f));
      s1 += v4.y * __builtin_amdgcn_rcpf(fmaf(e4.y, b4.y, 1.0f));
      s1 += v4.z * __builtin_amdgcn_rcpf(fmaf(e4.z, b4.z, 1.0f));
      s1 += v4.w * __builtin_amdgcn_rcpf(fmaf(e4.w, b4.w, 1.0f));
    }
    int t = tbase + tt + lane;
    scores[(size_t)(b * TD + j0 + w) * TE + t]     = V1 - 2.0f * s0;
    scores[(size_t)(b * TD + j0 + w + 8) * TE + t] = V1 - 2.0f * s1;
  }
}

// ---------- kernel 3: softmax over t -> e into d_out; also zeros this row's c slice ----------
__global__ __launch_bounds__(256) void softmax_kernel(
    const float* __restrict__ scores, float* __restrict__ eout,
    float4* __restrict__ c4) {
  __shared__ float red[4];
  int r = blockIdx.x, tid = threadIdx.x;
  if (tid < 32) c4[r * 32 + tid] = float4{0.f, 0.f, 0.f, 0.f};  // zero c for context's atomics
  const float* row = scores + (size_t)r * TE;
  float4 a = ((const float4*)row)[tid];
  float4 c = ((const float4*)row)[tid + 256];
  float m = fmaxf(fmaxf(fmaxf(a.x, a.y), fmaxf(a.z, a.w)),
                  fmaxf(fmaxf(c.x, c.y), fmaxf(c.z, c.w)));
  #pragma unroll
  for (int off = 32; off > 0; off >>= 1) m = fmaxf(m, __shfl_xor(m, off));
  int w = tid >> 6;
  if ((tid & 63) == 0) red[w] = m;
  __syncthreads();
  m = fmaxf(fmaxf(red[0], red[1]), fmaxf(red[2], red[3]));
  const float L2E = 1.4426950408889634f;
  a.x = __builtin_amdgcn_exp2f((a.x - m) * L2E);
  a.y = __builtin_amdgcn_exp2f((a.y - m) * L2E);
  a.z = __builtin_amdgcn_exp2f((a.z - m) * L2E);
  a.w = __builtin_amdgcn_exp2f((a.w - m) * L2E);
  c.x = __builtin_amdgcn_exp2f((c.x - m) * L2E);
  c.y = __builtin_amdgcn_exp2f((c.y - m) * L2E);
  c.z = __builtin_amdgcn_exp2f((c.z - m) * L2E);
  c.w = __builtin_amdgcn_exp2f((c.w - m) * L2E);
  float s = a.x + a.y + a.z + a.w + c.x + c.y + c.z + c.w;
  #pragma unroll
  for (int off = 32; off > 0; off >>= 1) s += __shfl_xor(s, off);
  __syncthreads();                 // red[] reuse
  if ((tid & 63) == 0) red[w] = s;
  __syncthreads();
  s = red[0] + red[1] + red[2] + red[3];
  float inv = 1.0f / s;            // precise div, once per thread
  a.x *= inv; a.y *= inv; a.z *= inv; a.w *= inv;
  c.x *= inv; c.y *= inv; c.z *= inv; c.w *= inv;
  float* orow = eout + (size_t)r * TE;
  ((float4*)orow)[tid] = a;
  ((float4*)orow)[tid + 256] = c;
}

// ---------- kernel 4: c[b,j,:] += sum_{t in chunk} e[b,j,t]*enc[b,t,:] (atomic combine) ----------
__global__ __launch_bounds__(512) void context_kernel(
    const float* __restrict__ enc, const float* __restrict__ e,
    float* __restrict__ cout) {
  __shared__ float Et[64 * 132];   // 33.8 KB enc tile [t][h], padded
  __shared__ float P[32 * 64];     // 8 KB e tile [j][t] (writes conflict-free, reads broadcast)
  int tid = threadIdx.x;
  int jt = blockIdx.x, tch = blockIdx.y, b = blockIdx.z;
  int j0 = jt * 32, t0 = tch * 256;
  int h = tid & 127, jg = tid >> 7;             // jg wave-uniform (0..3); 8 j's per thread
  float acc[8];
  #pragma unroll
  for (int p = 0; p < 8; ++p) acc[p] = 0.f;
  for (int tt = 0; tt < 256; tt += 64) {
    __syncthreads();
    const float4* eg = (const float4*)(enc + ((size_t)b * TE + t0 + tt) * H);
    #pragma unroll
    for (int i = 0; i < 4; ++i) {               // 64x128 floats = 2048 float4
      int f = tid + i * 512;
      int tr = f >> 5, kc = (f & 31) * 4;
      *(float4*)&Et[tr * 132 + kc] = eg[f];
    }
    #pragma unroll
    for (int pass = 0; pass < 4; ++pass) {      // 32 j x 64 t e-tile
      int j = pass * 8 + (tid >> 6), tl = tid & 63;
      P[j * 64 + tl] = e[(size_t)(b * TD + j0 + j) * TE + t0 + tt + tl];
    }
    __syncthreads();
    #pragma unroll 4
    for (int tl4 = 0; tl4 < 64; tl4 += 4) {
      float ec0 = Et[(tl4 + 0) * 132 + h];
      float ec1 = Et[(tl4 + 1) * 132 + h];
      float ec2 = Et[(tl4 + 2) * 132 + h];
      float ec3 = Et[(tl4 + 3) * 132 + h];
      #pragma unroll
      for (int p = 0; p < 8; ++p) {
        float4 p4 = *(const float4*)&P[(jg * 8 + p) * 64 + tl4];  // broadcast b128
        acc[p] += p4.x * ec0 + p4.y * ec1 + p4.z * ec2 + p4.w * ec3;
      }
    }
  }
  #pragma unroll
  for (int p = 0; p < 8; ++p)
    atomicAdd(&cout[(size_t)(b * TD + j0 + jg * 8 + p) * H + h], acc[p]);
}

extern "C" void kernel_launch(void* const* d_in, const int* in_sizes, int n_in,
                              void* d_out, int out_size, void* d_ws, size_t ws_size,
                              hipStream_t stream) {
  (void)in_sizes; (void)n_in; (void)out_size; (void)ws_size;
  const float* enc = (const float*)d_in[0];
  const float* dec = (const float*)d_in[1];
  const float* Wa  = (const float*)d_in[2];
  const float* Ua  = (const float*)d_in[3];
  const float* Va  = (const float*)d_in[4];

  float* ws     = (float*)d_ws;
  float* Ebuf   = ws;                                    //  2,097,152 f32 (8 MB)  e^{2*enc@W}
  float* Fbuf   = Ebuf + (size_t)B * TE * H;             //    262,144 f32 (1 MB)  e^{2*dec@U}
  float* scores = Fbuf + (size_t)B * TD * H;             //  4,194,304 f32 (16 MB)
  float* outc = (float*)d_out;                           // c [B,TD,H] fp32
  float* oute = outc + (size_t)B * TD * H;               // e [B,TD,TE] fp32

  proj_kernel<<<dim3((B * TE + B * TD) / 16), 256, 0, stream>>>(enc, dec, Wa, Ua, Ebuf, Fbuf);
  scores_kernel<<<dim3(4, 16, 8), 512, 0, stream>>>(Ebuf, Fbuf, Va, scores);
  softmax_kernel<<<dim3(B * TD), 256, 0, stream>>>(scores, oute, (float4*)outc);
  context_kernel<<<dim3(8, 8, 8), 512, 0, stream>>>(enc, oute, outc);
}